// Round 1
// baseline (43.457 us; speedup 1.0000x reference)
//
#include <hip/hip_runtime.h>

typedef __attribute__((ext_vector_type(8))) short bf16x8;   // 8 bf16 bit-patterns (4 VGPRs)
typedef __attribute__((ext_vector_type(4))) float f32x4;

// fp32 -> bf16 round-to-nearest-even (bit trick; inputs are finite randoms)
__device__ __forceinline__ short f2bf(float x) {
    unsigned u = __builtin_bit_cast(unsigned, x);
    u += 0x7fffu + ((u >> 16) & 1u);
    return (short)(u >> 16);
}

// One wave per batch row. Features padded 27 -> 32 (2 MFMA row-tiles of 16).
// Gram = A * A^T via mfma_f32_16x16x32_bf16: the same fragment feeds A- and
// B-operand roles, so layout-permutation errors on k cancel and symmetry of
// the Gram makes the result immune to C/D row<->col transposition.
__global__ __launch_bounds__(256) void fi_mfma_kernel(
    const float* __restrict__ bottom,   // [B, 128]
    const float* __restrict__ emb,      // [B, 26, 128]
    float* __restrict__ out,            // [B, 351]
    int B)
{
    const int wave = threadIdx.x >> 6;
    const int lane = threadIdx.x & 63;
    const int r = blockIdx.x * 4 + wave;        // batch row
    if (r >= B) return;

    const int lrow = lane & 15;                 // feature-within-tile (frag row/col)
    const int kgrp = lane >> 4;                 // 0..3 -> k offset group of 8

    // ---- load fp32 fragments straight from global (no LDS) ----
    // lane covers k = s*32 + kgrp*8 .. +7 (32B contiguous) of feature f = 16t+lrow
    f32x4 v[2][4][2];
    #pragma unroll
    for (int t = 0; t < 2; ++t) {
        const int f = 16 * t + lrow;
        const bool valid = (f < 27);
        const float* rowp = (f == 0)
            ? (bottom + (size_t)r * 128)
            : (emb + ((size_t)r * 26 + (valid ? (f - 1) : 0)) * 128);
        #pragma unroll
        for (int s = 0; s < 4; ++s) {
            const int k = s * 32 + kgrp * 8;
            if (valid) {
                v[t][s][0] = *(const f32x4*)(rowp + k);
                v[t][s][1] = *(const f32x4*)(rowp + k + 4);
            } else {
                v[t][s][0] = f32x4{0.f, 0.f, 0.f, 0.f};   // pad rows contribute only to
                v[t][s][1] = f32x4{0.f, 0.f, 0.f, 0.f};   // outputs we never store
            }
        }
    }

    // ---- convert to bf16 fragments ----
    bf16x8 fr[2][4];
    #pragma unroll
    for (int t = 0; t < 2; ++t)
        #pragma unroll
        for (int s = 0; s < 4; ++s)
            #pragma unroll
            for (int e = 0; e < 8; ++e)
                fr[t][s][e] = f2bf(v[t][s][e >> 2][e & 3]);

    // ---- Gram tiles: (0,0), (0,1), (1,1); accumulate over 4 K-steps ----
    f32x4 a00 = {0.f,0.f,0.f,0.f}, a01 = {0.f,0.f,0.f,0.f}, a11 = {0.f,0.f,0.f,0.f};
    #pragma unroll
    for (int s = 0; s < 4; ++s) {
        a00 = __builtin_amdgcn_mfma_f32_16x16x32_bf16(fr[0][s], fr[0][s], a00, 0, 0, 0);
        a01 = __builtin_amdgcn_mfma_f32_16x16x32_bf16(fr[0][s], fr[1][s], a01, 0, 0, 0);
        a11 = __builtin_amdgcn_mfma_f32_16x16x32_bf16(fr[1][s], fr[1][s], a11, 0, 0, 0);
    }

    // ---- scatter strict upper triangle: pairIdx(i,j) = i*(53-i)/2 + (j-i-1) ----
    // C/D map (m89-verified): col = lane&15, row = (lane>>4)*4 + reg
    float* orow = out + (size_t)r * 351;
    const int row0 = kgrp * 4;
    #pragma unroll
    for (int reg = 0; reg < 4; ++reg) {
        {   // tile (0,0): i,j in 0..15
            const int i = row0 + reg, j = lrow;
            if (i < j) orow[i * (53 - i) / 2 + (j - i - 1)] = a00[reg];
        }
        {   // tile (0,1): i in 0..15 (< j always), j in 16..31
            const int i = row0 + reg, j = 16 + lrow;
            if (j < 27) orow[i * (53 - i) / 2 + (j - i - 1)] = a01[reg];
        }
        {   // tile (1,1): i,j in 16..31
            const int i = 16 + row0 + reg, j = 16 + lrow;
            if (i < j && j < 27) orow[i * (53 - i) / 2 + (j - i - 1)] = a11[reg];
        }
    }
}

extern "C" void kernel_launch(void* const* d_in, const int* in_sizes, int n_in,
                              void* d_out, int out_size, void* d_ws, size_t ws_size,
                              hipStream_t stream) {
    const float* bottom = (const float*)d_in[0];   // (B, 128) fp32
    const float* emb    = (const float*)d_in[1];   // (B, 26, 128) fp32
    float* out          = (float*)d_out;           // (B, 351) fp32
    const int B = in_sizes[0] / 128;
    const int blocks = (B + 3) / 4;                // 4 rows (waves) per block
    fi_mfma_kernel<<<blocks, 256, 0, stream>>>(bottom, emb, out, B);
}

// Round 2
// 43.109 us; speedup vs baseline: 1.0081x; 1.0081x over previous
//
#include <hip/hip_runtime.h>

typedef __attribute__((ext_vector_type(8))) short bf16x8;   // 8 bf16 bit-patterns (4 VGPRs)
typedef __attribute__((ext_vector_type(4))) float f32x4;

// fp32 -> bf16 round-to-nearest-even (bit trick; inputs are finite randoms)
__device__ __forceinline__ short f2bf(float x) {
    unsigned u = __builtin_bit_cast(unsigned, x);
    u += 0x7fffu + ((u >> 16) & 1u);
    return (short)(u >> 16);
}

// One wave per batch row. Features padded 27 -> 32 (2 MFMA row-tiles of 16).
// Gram = A*A^T via mfma_f32_16x16x32_bf16; the same fragment feeds both
// operand roles, so ANY per-lane k-permutation cancels (sum over sigma(k) ==
// sum over k). We exploit that freedom to pick the k-chunk assignment that
// makes every load instruction cover FULL 64B cache lines:
//   instruction m (m=0..7): lane-group g (lane>>4) loads 16B at byte offset
//   m*64 + g*16 of its feature row -> the 4 groups cover line [m*64, m*64+64)
//   of each of the 16 feature rows. 16 fully-consumed lines per instruction
//   (vs 32 half-covered lines with the naive s*128+g*32 assignment).
__global__ __launch_bounds__(256) void fi_mfma_kernel(
    const float* __restrict__ bottom,   // [B, 128]
    const float* __restrict__ emb,      // [B, 26, 128]
    float* __restrict__ out,            // [B, 351]
    int B)
{
    const int wave = threadIdx.x >> 6;
    const int lane = threadIdx.x & 63;
    const int r = blockIdx.x * 4 + wave;        // batch row
    if (r >= B) return;

    const int lrow = lane & 15;                 // feature-within-tile (frag row/col)
    const int g    = lane >> 4;                 // lane group 0..3

    // ---- load fp32 straight from global: 8 full-line instructions per tile ----
    f32x4 w[2][8];
    #pragma unroll
    for (int t = 0; t < 2; ++t) {
        const int f = 16 * t + lrow;
        const bool valid = (f < 27);
        const float* rowp = (f == 0)
            ? (bottom + (size_t)r * 128)
            : (emb + ((size_t)r * 26 + (valid ? (f - 1) : 0)) * 128);
        #pragma unroll
        for (int m = 0; m < 8; ++m) {
            if (valid) {
                w[t][m] = *(const f32x4*)(rowp + m * 16 + g * 4);
            } else {
                w[t][m] = f32x4{0.f, 0.f, 0.f, 0.f};   // pad rows only feed outputs
            }                                           // we never store
        }
    }

    // ---- convert to bf16 fragments (order = load order; permutation cancels) ----
    bf16x8 fr[2][4];
    #pragma unroll
    for (int t = 0; t < 2; ++t)
        #pragma unroll
        for (int n = 0; n < 32; ++n)
            fr[t][n >> 3][n & 7] = f2bf(w[t][n >> 2][n & 3]);

    // ---- Gram tiles: (0,0), (0,1), (1,1); accumulate over 4 K-steps ----
    f32x4 a00 = {0.f,0.f,0.f,0.f}, a01 = {0.f,0.f,0.f,0.f}, a11 = {0.f,0.f,0.f,0.f};
    #pragma unroll
    for (int s = 0; s < 4; ++s) {
        a00 = __builtin_amdgcn_mfma_f32_16x16x32_bf16(fr[0][s], fr[0][s], a00, 0, 0, 0);
        a01 = __builtin_amdgcn_mfma_f32_16x16x32_bf16(fr[0][s], fr[1][s], a01, 0, 0, 0);
        a11 = __builtin_amdgcn_mfma_f32_16x16x32_bf16(fr[1][s], fr[1][s], a11, 0, 0, 0);
    }

    // ---- scatter strict upper triangle: pairIdx(i,j) = i*(53-i)/2 + (j-i-1) ----
    // C/D map (m89-verified): col = lane&15, row = (lane>>4)*4 + reg
    float* orow = out + (size_t)r * 351;
    const int row0 = g * 4;
    #pragma unroll
    for (int reg = 0; reg < 4; ++reg) {
        {   // tile (0,0): i,j in 0..15
            const int i = row0 + reg, j = lrow;
            if (i < j) orow[i * (53 - i) / 2 + (j - i - 1)] = a00[reg];
        }
        {   // tile (0,1): i in 0..15 (< j always), j in 16..31
            const int i = row0 + reg, j = 16 + lrow;
            if (j < 27) orow[i * (53 - i) / 2 + (j - i - 1)] = a01[reg];
        }
        {   // tile (1,1): i,j in 16..31
            const int i = 16 + row0 + reg, j = 16 + lrow;
            if (i < j && j < 27) orow[i * (53 - i) / 2 + (j - i - 1)] = a11[reg];
        }
    }
}

extern "C" void kernel_launch(void* const* d_in, const int* in_sizes, int n_in,
                              void* d_out, int out_size, void* d_ws, size_t ws_size,
                              hipStream_t stream) {
    const float* bottom = (const float*)d_in[0];   // (B, 128) fp32
    const float* emb    = (const float*)d_in[1];   // (B, 26, 128) fp32
    float* out          = (float*)d_out;           // (B, 351) fp32
    const int B = in_sizes[0] / 128;
    const int blocks = (B + 3) / 4;                // 4 rows (waves) per block
    fi_mfma_kernel<<<blocks, 256, 0, stream>>>(bottom, emb, out, B);
}